// Round 4
// baseline (428.731 us; speedup 1.0000x reference)
//
#include <hip/hip_runtime.h>
#include <hip/hip_bf16.h>
#include <stdint.h>

#define D_MODEL 1024
#define S_LEN   2048
#define BATCH   4
#define NH      8
#define DK      128

typedef __attribute__((ext_vector_type(8))) __bf16 bf16x8;
typedef __attribute__((ext_vector_type(4))) float  f32x4;

__device__ __forceinline__ f32x4 mfma16(bf16x8 a, bf16x8 b, f32x4 c) {
  return __builtin_amdgcn_mfma_f32_16x16x32_bf16(a, b, c, 0, 0, 0);
}

// async global->LDS, 16B per lane; lds base is wave-uniform, HW writes
// ldsbase + lane*16 (guide §5, m97/m104).
__device__ __forceinline__ void gld_lds16(const void* g, void* l) {
  __builtin_amdgcn_global_load_lds(
      (const __attribute__((address_space(1))) void*)g,
      (__attribute__((address_space(3))) void*)l, 16, 0, 0);
}

__device__ __forceinline__ bf16x8 cvt8(f32x4 a, f32x4 b) {
  bf16x8 r;
#pragma unroll
  for (int j = 0; j < 4; ++j) {
    __hip_bfloat16 t0 = __float2bfloat16(a[j]);
    __hip_bfloat16 t1 = __float2bfloat16(b[j]);
    r[j]     = *reinterpret_cast<__bf16*>(&t0);
    r[4 + j] = *reinterpret_cast<__bf16*>(&t1);
  }
  return r;
}

#define ATTN_SCALE 0.08838834764831845f  // 1/sqrt(128), folded into Wq/bq

// ---------------------------------------------------------------------------
// Kernel 0: transpose+convert weights W[k][n] fp32 -> Wt[n][k] bf16.
// Wq pre-scaled by 1/sqrt(dk).
// ---------------------------------------------------------------------------
__global__ void wtrans_kernel(const float* __restrict__ Wq,
                              const float* __restrict__ Wk,
                              const float* __restrict__ Wv,
                              __hip_bfloat16* __restrict__ Wt) {
  __shared__ __hip_bfloat16 tile[32][33];
  const int w = blockIdx.z;
  const float* src = (w == 0) ? Wq : (w == 1) ? Wk : Wv;
  const float sc = (w == 0) ? ATTN_SCALE : 1.0f;
  __hip_bfloat16* dst = Wt + (size_t)w * D_MODEL * D_MODEL;
  const int tx = threadIdx.x, ty = threadIdx.y;
  int x = blockIdx.x * 32 + tx;
  int y = blockIdx.y * 32 + ty;
  for (int i = 0; i < 32; i += 8)
    tile[ty + i][tx] = __float2bfloat16(src[(size_t)(y + i) * D_MODEL + x] * sc);
  __syncthreads();
  x = blockIdx.y * 32 + tx;
  y = blockIdx.x * 32 + ty;
  for (int i = 0; i < 32; i += 8)
    dst[(size_t)(y + i) * D_MODEL + x] = tile[tx][ty + i];
}

// ---------------------------------------------------------------------------
// Kernel 1: QKV projection GEMM, A staged DIRECTLY from fp32 input (no cvt
// pass). A LDS layout XOR-swizzled at 16B-chunk granularity:
//   slot(row, kc) = (row<<3) | (kc ^ (row&7)),  kc = k/4 (0..7)
// -> staging coalesced per 128B row, fragment reads 2-way-conflict-free.
// fp32 -> bf16 conversion at fragment-read time.
// Q,K -> [B,H,S,dk]; V -> transposed [B,H,dk,S].
// ---------------------------------------------------------------------------
__global__ __launch_bounds__(256) void qkv_gemm_kernel(
    const float* __restrict__ xq, const float* __restrict__ xk,
    const float* __restrict__ xv,
    const float* __restrict__ bq, const float* __restrict__ bk,
    const float* __restrict__ bv,
    const __hip_bfloat16* __restrict__ Wt,
    __hip_bfloat16* __restrict__ Qo, __hip_bfloat16* __restrict__ Ko,
    __hip_bfloat16* __restrict__ Vo) {
  const int which = blockIdx.z;
  const float* X = (which == 0) ? xq : (which == 1) ? xk : xv;
  const __hip_bfloat16* W = Wt + (size_t)which * D_MODEL * D_MODEL;
  const float* bias = (which == 0) ? bq : (which == 1) ? bk : bv;
  const float bscale = (which == 0) ? ATTN_SCALE : 1.0f;

  __shared__ __align__(16) float Af[128 * 32];            // 16 KB, swizzled
  __shared__ __align__(16) __hip_bfloat16 Bsm[128 * 32];  // 8 KB

  const int tid  = threadIdx.x;
  const int lane = tid & 63;
  const int wv   = tid >> 6;
  const int lo16 = lane & 15;
  const int hi4  = lane >> 4;
  const int m0 = blockIdx.y * 128;
  const int n0 = blockIdx.x * 128;
  const int wm = (wv >> 1) * 64;
  const int wn = (wv & 1) * 64;

  f32x4 acc[4][4];
  const f32x4 z4 = {0.f, 0.f, 0.f, 0.f};
  for (int i = 0; i < 4; ++i)
    for (int j = 0; j < 4; ++j) acc[i][j] = z4;

  for (int k0 = 0; k0 < D_MODEL; k0 += 32) {
    __syncthreads();
    // A: 1024 chunks of 4 fp32; slot c holds (row=c>>3, kc=(c&7)^(row&7))
    for (int it = 0; it < 4; ++it) {
      const int cbase = it * 256 + wv * 64;
      const int c = cbase + lane;
      const int row = c >> 3;
      const int kc = (c & 7) ^ (row & 7);
      gld_lds16(X + (size_t)(m0 + row) * D_MODEL + k0 + kc * 4,
                &Af[cbase * 4]);
    }
    // B: bf16, row-major [128][32]
    for (int it = 0; it < 2; ++it) {
      const int cbase = it * 256 + wv * 64;
      const int c = cbase + lane;
      gld_lds16(W + (size_t)(n0 + (c >> 2)) * D_MODEL + k0 + (c & 3) * 8,
                &Bsm[cbase * 8]);
    }
    __syncthreads();

    bf16x8 af[4], bfr[4];
    for (int i = 0; i < 4; ++i) {
      const int r = wm + 16 * i + lo16;
      const int s0 = (r << 3) | ((2 * hi4) ^ (r & 7));
      const int s1 = (r << 3) | ((2 * hi4 + 1) ^ (r & 7));
      const f32x4 a0 = *(const f32x4*)&Af[s0 * 4];
      const f32x4 a1 = *(const f32x4*)&Af[s1 * 4];
      af[i] = cvt8(a0, a1);
    }
    for (int j = 0; j < 4; ++j)
      bfr[j] = *(const bf16x8*)&Bsm[(wn + 16 * j + lo16) * 32 + hi4 * 8];
    for (int i = 0; i < 4; ++i)
      for (int j = 0; j < 4; ++j)
        acc[i][j] = mfma16(af[i], bfr[j], acc[i][j]);
  }

  // epilogue: C/D layout col = lane&15, row = (lane>>4)*4 + reg  (m89/m91)
  const int b = m0 >> 11;  // 2048 rows per batch, block never straddles
  for (int j = 0; j < 4; ++j) {
    const int n = n0 + wn + j * 16 + lo16;
    const float bval = bias[n] * bscale;
    const int h = n >> 7;
    const int d = n & 127;
    for (int i = 0; i < 4; ++i) {
      for (int r = 0; r < 4; ++r) {
        const int m = m0 + wm + 16 * i + hi4 * 4 + r;
        const int s = m & (S_LEN - 1);
        const __hip_bfloat16 ob = __float2bfloat16(acc[i][j][r] + bval);
        if (which == 0)
          Qo[((size_t)(b * NH + h) * S_LEN + s) * DK + d] = ob;
        else if (which == 1)
          Ko[((size_t)(b * NH + h) * S_LEN + s) * DK + d] = ob;
        else
          Vo[((size_t)(b * NH + h) * DK + d) * S_LEN + s] = ob;
      }
    }
  }
}

// ---------------------------------------------------------------------------
// Kernel 2: causal flash attention.
//  - block = one 128-row q-tile, 4 waves x 32 rows -> no intra-block idle
//    (<=2.3% on the longest tile). Longest tiles launched first.
//  - kv tiles of 32, double-buffered LDS, prefetch right after the single
//    per-step barrier.
//  - constant-max softmax: p = exp(s - 8); row-sum reduced once at the end.
//  - P C-layout -> A-layout via wave-local LDS + s_waitcnt lgkmcnt(0).
// ---------------------------------------------------------------------------
__global__ __launch_bounds__(256) void attn_kernel(
    const __hip_bfloat16* __restrict__ Qw, const __hip_bfloat16* __restrict__ Kw,
    const __hip_bfloat16* __restrict__ Vtw, __hip_bfloat16* __restrict__ Og) {
  const int t = 15 - blockIdx.x;        // 128-row q-tile, longest first
  const int h = blockIdx.y;
  const int b = blockIdx.z;
  const int tid  = threadIdx.x;
  const int lane = tid & 63;
  const int wv   = tid >> 6;
  const int lo16 = lane & 15;
  const int hi4  = lane >> 4;

  const int qrow0  = t * 128 + wv * 32;  // this wave's 32 q rows
  const int ns_w   = 4 * t + wv + 1;     // active kv32 steps for this wave
  const int nsteps = 4 * t + 4;          // block loop bound

  const size_t bh = (size_t)(b * NH + h);
  const __hip_bfloat16* Qp = Qw + bh * S_LEN * DK;
  const __hip_bfloat16* Kp = Kw + bh * S_LEN * DK;
  const __hip_bfloat16* Vp = Vtw + bh * DK * S_LEN;  // [dk][S]

  __shared__ __align__(16) __hip_bfloat16 Ksm[2][32 * 128];  // [dchunk16][kv32]
  __shared__ __align__(16) __hip_bfloat16 Vsm[2][128 * 32];  // [kvchunk4][d128]
  __shared__ __align__(16) __hip_bfloat16 Psm[4][32 * 40];   // per-wave P

  // Q fragments: A[m=lo16][k=hi4*8+j]; 2 m-groups x 4 k-steps cover 32q x 128d
  bf16x8 qf[2][4];
  for (int m = 0; m < 2; ++m)
    for (int kk = 0; kk < 4; ++kk)
      qf[m][kk] = *(const bf16x8*)&Qp[(size_t)(qrow0 + m * 16 + lo16) * DK +
                                      kk * 32 + hi4 * 8];

  f32x4 oacc[2][8];
  const f32x4 z4 = {0.f, 0.f, 0.f, 0.f};
  for (int m = 0; m < 2; ++m)
    for (int j = 0; j < 8; ++j) oacc[m][j] = z4;
  float lsum[2][4];
  for (int m = 0; m < 2; ++m)
    for (int i = 0; i < 4; ++i) lsum[m][i] = 0.f;

  auto stage = [&](int st, int buf) {
    const int kv0 = st << 5;
    for (int it = 0; it < 2; ++it) {
      const int cbase = it * 256 + wv * 64;
      const int c = cbase + lane;
      gld_lds16(Kp + (size_t)(kv0 + (c & 31)) * DK + (c >> 5) * 8,
                &Ksm[buf][cbase * 8]);
      gld_lds16(Vp + (size_t)(c & 127) * S_LEN + kv0 + (c >> 7) * 8,
                &Vsm[buf][cbase * 8]);
    }
  };

  stage(0, 0);

  for (int st = 0; st < nsteps; ++st) {
    __syncthreads();  // drains vmcnt: buf[st&1] ready, other buffer free
    if (st + 1 < nsteps) stage(st + 1, (st + 1) & 1);

    if (st < ns_w) {
      const __hip_bfloat16* Kb = Ksm[st & 1];
      const __hip_bfloat16* Vb = Vsm[st & 1];

      // QK^T: S[32q][32kv] as 2m x 2kn 16x16 tiles
      bf16x8 kf[2][4];
      for (int kn = 0; kn < 2; ++kn)
        for (int kk = 0; kk < 4; ++kk)
          kf[kn][kk] = *(const bf16x8*)&Kb[((kk * 4 + hi4) * 32 + kn * 16 + lo16) * 8];
      f32x4 sc[2][2];
      for (int m = 0; m < 2; ++m)
        for (int kn = 0; kn < 2; ++kn) {
          f32x4 s4 = z4;
          for (int kk = 0; kk < 4; ++kk)
            s4 = mfma16(qf[m][kk], kf[kn][kk], s4);
          sc[m][kn] = s4;
        }

      // constant-max softmax; C/D row = hi4*4+reg, col = lo16
      const int kv0 = st << 5;
      const bool do_mask = (st == ns_w - 1);  // only the diagonal step masks
      for (int m = 0; m < 2; ++m) {
        for (int i = 0; i < 4; ++i) {
          const int qg = qrow0 + m * 16 + hi4 * 4 + i;
          float s0 = sc[m][0][i];
          float s1 = sc[m][1][i];
          if (do_mask) {
            if (kv0 + lo16 > qg)      s0 = -1.0e30f;
            if (kv0 + 16 + lo16 > qg) s1 = -1.0e30f;
          }
          const float p0 = __expf(s0 - 8.f);
          const float p1 = __expf(s1 - 8.f);
          lsum[m][i] += p0 + p1;
          const int prw = m * 16 + hi4 * 4 + i;
          Psm[wv][prw * 40 + lo16]      = __float2bfloat16(p0);
          Psm[wv][prw * 40 + 16 + lo16] = __float2bfloat16(p1);
        }
      }
      // wave-local LDS round-trip: order + drain without __syncthreads
      asm volatile("s_waitcnt lgkmcnt(0)" ::: "memory");

      // PV: A = P[q16][kv32] per m-group, B = Vt[d][kv]; V frags shared by m
      bf16x8 pf[2];
      for (int m = 0; m < 2; ++m)
        pf[m] = *(const bf16x8*)&Psm[wv][(m * 16 + lo16) * 40 + hi4 * 8];
      for (int j = 0; j < 8; ++j) {
        const bf16x8 vf = *(const bf16x8*)&Vb[(hi4 * 128 + j * 16 + lo16) * 8];
        oacc[0][j] = mfma16(pf[0], vf, oacc[0][j]);
        oacc[1][j] = mfma16(pf[1], vf, oacc[1][j]);
      }
    }
  }

  // final row-sum reduce (over 16-lane groups) + O write
  for (int m = 0; m < 2; ++m) {
    for (int i = 0; i < 4; ++i) {
      float l = lsum[m][i];
      l += __shfl_xor(l, 1);
      l += __shfl_xor(l, 2);
      l += __shfl_xor(l, 4);
      l += __shfl_xor(l, 8);
      const float inv = 1.0f / l;
      const int qg = qrow0 + m * 16 + hi4 * 4 + i;
      __hip_bfloat16* orow = Og + ((size_t)b * S_LEN + qg) * D_MODEL + h * DK;
      for (int j = 0; j < 8; ++j)
        orow[j * 16 + lo16] = __float2bfloat16(oacc[m][j][i] * inv);
    }
  }
}

// ---------------------------------------------------------------------------
// Kernel 3: residual + LayerNorm, one block per row, fp32 I/O
// ---------------------------------------------------------------------------
__global__ __launch_bounds__(256) void ln_kernel(
    const __hip_bfloat16* __restrict__ Og, const float* __restrict__ resid_in,
    const float* __restrict__ gamma, const float* __restrict__ beta,
    float* __restrict__ out) {
  const int row = blockIdx.x;
  const __hip_bfloat16* orow = Og + (size_t)row * D_MODEL;
  const float* qrow = resid_in + (size_t)row * D_MODEL;
  const int tid = threadIdx.x;
  float v[4];
  float s = 0.f, ss = 0.f;
  for (int i = 0; i < 4; ++i) {
    const int idx = tid + i * 256;
    const float x = __bfloat162float(orow[idx]) + qrow[idx];
    v[i] = x; s += x; ss += x * x;
  }
  for (int m = 1; m < 64; m <<= 1) { s += __shfl_xor(s, m); ss += __shfl_xor(ss, m); }
  __shared__ float red[8];
  const int wv = tid >> 6, lane = tid & 63;
  if (lane == 0) { red[wv] = s; red[4 + wv] = ss; }
  __syncthreads();
  s  = red[0] + red[1] + red[2] + red[3];
  ss = red[4] + red[5] + red[6] + red[7];
  const float mu  = s * (1.0f / D_MODEL);
  const float var = ss * (1.0f / D_MODEL) - mu * mu;
  const float rstd = rsqrtf(var + 1e-6f);
  float* outrow = out + (size_t)row * D_MODEL;
  for (int i = 0; i < 4; ++i) {
    const int idx = tid + i * 256;
    outrow[idx] = (v[i] - mu) * rstd * gamma[idx] + beta[idx];
  }
}

// ---------------------------------------------------------------------------
extern "C" void kernel_launch(void* const* d_in, const int* in_sizes, int n_in,
                              void* d_out, int out_size, void* d_ws, size_t ws_size,
                              hipStream_t stream) {
  const float* queries = (const float*)d_in[0];
  const float* keys    = (const float*)d_in[1];
  const float* values  = (const float*)d_in[2];
  const float* Wq = (const float*)d_in[3];
  const float* bq = (const float*)d_in[4];
  const float* Wk = (const float*)d_in[5];
  const float* bk = (const float*)d_in[6];
  const float* Wv = (const float*)d_in[7];
  const float* bv = (const float*)d_in[8];
  const float* gamma = (const float*)d_in[9];
  const float* beta  = (const float*)d_in[10];

  char* ws = (char*)d_ws;
  const size_t WT_BYTES  = (size_t)3 * D_MODEL * D_MODEL * 2;      // 6 MB
  const size_t QKV_BYTES = (size_t)BATCH * NH * S_LEN * DK * 2;    // 16 MB
  __hip_bfloat16* Wt  = (__hip_bfloat16*)ws;
  __hip_bfloat16* Qws = (__hip_bfloat16*)(ws + WT_BYTES);
  __hip_bfloat16* Kws = (__hip_bfloat16*)(ws + WT_BYTES + QKV_BYTES);
  __hip_bfloat16* Vws = (__hip_bfloat16*)(ws + WT_BYTES + 2 * QKV_BYTES);
  __hip_bfloat16* Ogs = (__hip_bfloat16*)(ws + WT_BYTES + 3 * QKV_BYTES);
  // peak ws use: 6 + 64 = 70 MB

  wtrans_kernel<<<dim3(32, 32, 3), dim3(32, 8), 0, stream>>>(Wq, Wk, Wv, Wt);
  qkv_gemm_kernel<<<dim3(D_MODEL / 128, BATCH * S_LEN / 128, 3), 256, 0, stream>>>(
      queries, keys, values, bq, bk, bv, Wt, Qws, Kws, Vws);
  attn_kernel<<<dim3(16, NH, BATCH), 256, 0, stream>>>(Qws, Kws, Vws, Ogs);
  ln_kernel<<<dim3(BATCH * S_LEN), 256, 0, stream>>>(Ogs, queries, gamma, beta,
                                                     (float*)d_out);
}

// Round 5
// 417.586 us; speedup vs baseline: 1.0267x; 1.0267x over previous
//
#include <hip/hip_runtime.h>
#include <hip/hip_bf16.h>
#include <stdint.h>

#define D_MODEL 1024
#define S_LEN   2048
#define BATCH   4
#define NH      8
#define DK      128

typedef __attribute__((ext_vector_type(8))) __bf16 bf16x8;
typedef __attribute__((ext_vector_type(4))) float  f32x4;

__device__ __forceinline__ f32x4 mfma16(bf16x8 a, bf16x8 b, f32x4 c) {
  return __builtin_amdgcn_mfma_f32_16x16x32_bf16(a, b, c, 0, 0, 0);
}

// async global->LDS, 16B per lane; lds base is wave-uniform, HW writes
// ldsbase + lane*16 (guide §5, m97/m104).
__device__ __forceinline__ void gld_lds16(const void* g, void* l) {
  __builtin_amdgcn_global_load_lds(
      (const __attribute__((address_space(1))) void*)g,
      (__attribute__((address_space(3))) void*)l, 16, 0, 0);
}

#define ATTN_SCALE 0.08838834764831845f  // 1/sqrt(128), folded into Wq/bq

// ---------------------------------------------------------------------------
// Kernel 0a: fp32 -> bf16 convert of the three activation tensors.
// Re-reading bf16 (x8 refetch in the GEMM) beats re-reading fp32: the 144 MB
// one-time cost here saves 384 MB of refetch potential. [R4 post-mortem]
// ---------------------------------------------------------------------------
__global__ __launch_bounds__(256) void cvt_kernel(
    const float* __restrict__ x0, const float* __restrict__ x1,
    const float* __restrict__ x2, __hip_bfloat16* __restrict__ out) {
  const size_t N = (size_t)BATCH * S_LEN * D_MODEL;  // 8M elems
  const int w = blockIdx.y;
  const float* src = (w == 0) ? x0 : (w == 1) ? x1 : x2;
  __hip_bfloat16* dst = out + (size_t)w * N;
  const size_t i = ((size_t)blockIdx.x * 256 + threadIdx.x) * 4;
  const float4 v = *(const float4*)(src + i);
  *(__hip_bfloat162*)(dst + i)     = __float22bfloat162_rn(make_float2(v.x, v.y));
  *(__hip_bfloat162*)(dst + i + 2) = __float22bfloat162_rn(make_float2(v.z, v.w));
}

// ---------------------------------------------------------------------------
// Kernel 0b: transpose+convert weights W[k][n] fp32 -> Wt[n][k] bf16.
// Wq pre-scaled by 1/sqrt(dk).
// ---------------------------------------------------------------------------
__global__ void wtrans_kernel(const float* __restrict__ Wq,
                              const float* __restrict__ Wk,
                              const float* __restrict__ Wv,
                              __hip_bfloat16* __restrict__ Wt) {
  __shared__ __hip_bfloat16 tile[32][33];
  const int w = blockIdx.z;
  const float* src = (w == 0) ? Wq : (w == 1) ? Wk : Wv;
  const float sc = (w == 0) ? ATTN_SCALE : 1.0f;
  __hip_bfloat16* dst = Wt + (size_t)w * D_MODEL * D_MODEL;
  const int tx = threadIdx.x, ty = threadIdx.y;
  int x = blockIdx.x * 32 + tx;
  int y = blockIdx.y * 32 + ty;
  for (int i = 0; i < 32; i += 8)
    tile[ty + i][tx] = __float2bfloat16(src[(size_t)(y + i) * D_MODEL + x] * sc);
  __syncthreads();
  x = blockIdx.y * 32 + tx;
  y = blockIdx.x * 32 + ty;
  for (int i = 0; i < 32; i += 8)
    dst[(size_t)(y + i) * D_MODEL + x] = tile[tx][ty + i];
}

// ---------------------------------------------------------------------------
// Kernel 1: QKV projection GEMM (m97 structure, bf16 staged A and B).
// XCD-grouped block order: flat grid; the 8 n-blocks of one m-tile map to the
// SAME virtual XCD (flat&7) consecutively, so the A-tile is fetched once into
// that XCD's L2 and reused by the other 7 blocks (R4: they landed on 8
// different XCDs -> 397 MB FETCH).
// Q,K -> [B,H,S,dk]; V -> transposed [B,H,dk,S].
// ---------------------------------------------------------------------------
__global__ __launch_bounds__(256) void qkv_gemm_kernel(
    const __hip_bfloat16* __restrict__ Xbf,
    const float* __restrict__ bq, const float* __restrict__ bk,
    const float* __restrict__ bv,
    const __hip_bfloat16* __restrict__ Wt,
    __hip_bfloat16* __restrict__ Qo, __hip_bfloat16* __restrict__ Ko,
    __hip_bfloat16* __restrict__ Vo) {
  // remap: flat -> (xcd, n_t, m-group) -> (slice, m_t, n_t)
  const int flat = blockIdx.x;          // 0..1535
  const int xcd  = flat & 7;
  const int idx  = flat >> 3;           // 0..191
  const int n_t  = idx & 7;
  const int mg   = idx >> 3;            // 0..23
  const int pair = xcd * 24 + mg;       // 0..191 = 64 m-tiles x 3 slices
  const int which = pair >> 6;
  const int m_t   = pair & 63;

  const size_t N = (size_t)BATCH * S_LEN * D_MODEL;
  const __hip_bfloat16* X = Xbf + (size_t)which * N;
  const __hip_bfloat16* W = Wt + (size_t)which * D_MODEL * D_MODEL;
  const float* bias = (which == 0) ? bq : (which == 1) ? bk : bv;
  const float bscale = (which == 0) ? ATTN_SCALE : 1.0f;

  __shared__ __align__(16) __hip_bfloat16 Asm[128 * 32];
  __shared__ __align__(16) __hip_bfloat16 Bsm[128 * 32];

  const int tid  = threadIdx.x;
  const int lane = tid & 63;
  const int wv   = tid >> 6;
  const int lo16 = lane & 15;
  const int hi4  = lane >> 4;
  const int m0 = m_t * 128;
  const int n0 = n_t * 128;
  const int wm = (wv >> 1) * 64;
  const int wn = (wv & 1) * 64;

  f32x4 acc[4][4];
  const f32x4 z4 = {0.f, 0.f, 0.f, 0.f};
  for (int i = 0; i < 4; ++i)
    for (int j = 0; j < 4; ++j) acc[i][j] = z4;

  for (int k0 = 0; k0 < D_MODEL; k0 += 32) {
    __syncthreads();
    for (int it = 0; it < 2; ++it) {
      const int cbase = it * 256 + wv * 64;
      const int c = cbase + lane;
      gld_lds16(X + (size_t)(m0 + (c >> 2)) * D_MODEL + k0 + (c & 3) * 8,
                &Asm[cbase * 8]);
      gld_lds16(W + (size_t)(n0 + (c >> 2)) * D_MODEL + k0 + (c & 3) * 8,
                &Bsm[cbase * 8]);
    }
    __syncthreads();

    bf16x8 af[4], bfr[4];
    for (int i = 0; i < 4; ++i)
      af[i] = *(const bf16x8*)&Asm[(wm + 16 * i + lo16) * 32 + hi4 * 8];
    for (int j = 0; j < 4; ++j)
      bfr[j] = *(const bf16x8*)&Bsm[(wn + 16 * j + lo16) * 32 + hi4 * 8];
    for (int i = 0; i < 4; ++i)
      for (int j = 0; j < 4; ++j)
        acc[i][j] = mfma16(af[i], bfr[j], acc[i][j]);
  }

  // epilogue: C/D layout col = lane&15, row = (lane>>4)*4 + reg  (m89/m91)
  const int b = m0 >> 11;  // 2048 rows per batch, block never straddles
  for (int j = 0; j < 4; ++j) {
    const int n = n0 + wn + j * 16 + lo16;
    const float bval = bias[n] * bscale;
    const int h = n >> 7;
    const int d = n & 127;
    for (int i = 0; i < 4; ++i) {
      for (int r = 0; r < 4; ++r) {
        const int m = m0 + wm + 16 * i + hi4 * 4 + r;
        const int s = m & (S_LEN - 1);
        const __hip_bfloat16 ob = __float2bfloat16(acc[i][j][r] + bval);
        if (which == 0)
          Qo[((size_t)(b * NH + h) * S_LEN + s) * DK + d] = ob;
        else if (which == 1)
          Ko[((size_t)(b * NH + h) * S_LEN + s) * DK + d] = ob;
        else
          Vo[((size_t)(b * NH + h) * DK + d) * S_LEN + s] = ob;
      }
    }
  }
}

// ---------------------------------------------------------------------------
// Kernel 2: causal flash attention, 2-wave blocks for occupancy.
//  - block = one 64-row q-tile, 2 waves x 32 rows; grid 1024 blocks ->
//    4 blocks/CU (LDS 37 KB), ~8 waves/CU vs ~5.4 in the 4-wave version.
//  - kv tiles of 32, double-buffered LDS, prefetch right after the single
//    per-step barrier.
//  - constant-max softmax: p = exp(s - 8); row-sum reduced once at the end.
//  - P C-layout -> A-layout via wave-local LDS + s_waitcnt lgkmcnt(0).
// ---------------------------------------------------------------------------
__global__ __launch_bounds__(128) void attn_kernel(
    const __hip_bfloat16* __restrict__ Qw, const __hip_bfloat16* __restrict__ Kw,
    const __hip_bfloat16* __restrict__ Vtw, __hip_bfloat16* __restrict__ Og) {
  const int t = 31 - blockIdx.x;        // 64-row q-tile, longest first
  const int h = blockIdx.y;
  const int b = blockIdx.z;
  const int tid  = threadIdx.x;
  const int lane = tid & 63;
  const int wv   = tid >> 6;            // 0..1
  const int lo16 = lane & 15;
  const int hi4  = lane >> 4;

  const int qrow0  = t * 64 + wv * 32;   // this wave's 32 q rows
  const int ns_w   = 2 * t + wv + 1;     // active kv32 steps for this wave
  const int nsteps = 2 * t + 2;          // block loop bound

  const size_t bh = (size_t)(b * NH + h);
  const __hip_bfloat16* Qp = Qw + bh * S_LEN * DK;
  const __hip_bfloat16* Kp = Kw + bh * S_LEN * DK;
  const __hip_bfloat16* Vp = Vtw + bh * DK * S_LEN;  // [dk][S]

  __shared__ __align__(16) __hip_bfloat16 Ksm[2][32 * 128];  // [dchunk16][kv32]
  __shared__ __align__(16) __hip_bfloat16 Vsm[2][128 * 32];  // [kvchunk4][d128]
  __shared__ __align__(16) __hip_bfloat16 Psm[2][32 * 40];   // per-wave P

  // Q fragments: A[m=lo16][k=hi4*8+j]; 2 m-groups x 4 k-steps cover 32q x 128d
  bf16x8 qf[2][4];
  for (int m = 0; m < 2; ++m)
    for (int kk = 0; kk < 4; ++kk)
      qf[m][kk] = *(const bf16x8*)&Qp[(size_t)(qrow0 + m * 16 + lo16) * DK +
                                      kk * 32 + hi4 * 8];

  f32x4 oacc[2][8];
  const f32x4 z4 = {0.f, 0.f, 0.f, 0.f};
  for (int m = 0; m < 2; ++m)
    for (int j = 0; j < 8; ++j) oacc[m][j] = z4;
  float lsum[2][4];
  for (int m = 0; m < 2; ++m)
    for (int i = 0; i < 4; ++i) lsum[m][i] = 0.f;

  // stage kv tile `st` into buffer `buf`; 512 chunks of 16B over 128 threads
  auto stage = [&](int st, int buf) {
    const int kv0 = st << 5;
    for (int it = 0; it < 4; ++it) {
      const int cbase = it * 128 + wv * 64;
      const int c = cbase + lane;
      gld_lds16(Kp + (size_t)(kv0 + (c & 31)) * DK + (c >> 5) * 8,
                &Ksm[buf][cbase * 8]);
      gld_lds16(Vp + (size_t)(c & 127) * S_LEN + kv0 + (c >> 7) * 8,
                &Vsm[buf][cbase * 8]);
    }
  };

  stage(0, 0);

  for (int st = 0; st < nsteps; ++st) {
    __syncthreads();  // drains vmcnt: buf[st&1] ready, other buffer free
    if (st + 1 < nsteps) stage(st + 1, (st + 1) & 1);

    if (st < ns_w) {
      const __hip_bfloat16* Kb = Ksm[st & 1];
      const __hip_bfloat16* Vb = Vsm[st & 1];

      // QK^T: S[32q][32kv] as 2m x 2kn 16x16 tiles
      bf16x8 kf[2][4];
      for (int kn = 0; kn < 2; ++kn)
        for (int kk = 0; kk < 4; ++kk)
          kf[kn][kk] = *(const bf16x8*)&Kb[((kk * 4 + hi4) * 32 + kn * 16 + lo16) * 8];
      f32x4 sc[2][2];
      for (int m = 0; m < 2; ++m)
        for (int kn = 0; kn < 2; ++kn) {
          f32x4 s4 = z4;
          for (int kk = 0; kk < 4; ++kk)
            s4 = mfma16(qf[m][kk], kf[kn][kk], s4);
          sc[m][kn] = s4;
        }

      // constant-max softmax; C/D row = hi4*4+reg, col = lo16
      const int kv0 = st << 5;
      const bool do_mask = (st == ns_w - 1);  // only the diagonal step masks
      for (int m = 0; m < 2; ++m) {
        for (int i = 0; i < 4; ++i) {
          const int qg = qrow0 + m * 16 + hi4 * 4 + i;
          float s0 = sc[m][0][i];
          float s1 = sc[m][1][i];
          if (do_mask) {
            if (kv0 + lo16 > qg)      s0 = -1.0e30f;
            if (kv0 + 16 + lo16 > qg) s1 = -1.0e30f;
          }
          const float p0 = __expf(s0 - 8.f);
          const float p1 = __expf(s1 - 8.f);
          lsum[m][i] += p0 + p1;
          const int prw = m * 16 + hi4 * 4 + i;
          Psm[wv][prw * 40 + lo16]      = __float2bfloat16(p0);
          Psm[wv][prw * 40 + 16 + lo16] = __float2bfloat16(p1);
        }
      }
      // wave-local LDS round-trip: order + drain without __syncthreads
      asm volatile("s_waitcnt lgkmcnt(0)" ::: "memory");

      // PV: A = P[q16][kv32] per m-group, B = Vt[d][kv]; V frags shared by m
      bf16x8 pf[2];
      for (int m = 0; m < 2; ++m)
        pf[m] = *(const bf16x8*)&Psm[wv][(m * 16 + lo16) * 40 + hi4 * 8];
      for (int j = 0; j < 8; ++j) {
        const bf16x8 vf = *(const bf16x8*)&Vb[(hi4 * 128 + j * 16 + lo16) * 8];
        oacc[0][j] = mfma16(pf[0], vf, oacc[0][j]);
        oacc[1][j] = mfma16(pf[1], vf, oacc[1][j]);
      }
    }
  }

  // final row-sum reduce (over 16-lane groups) + O write
  for (int m = 0; m < 2; ++m) {
    for (int i = 0; i < 4; ++i) {
      float l = lsum[m][i];
      l += __shfl_xor(l, 1);
      l += __shfl_xor(l, 2);
      l += __shfl_xor(l, 4);
      l += __shfl_xor(l, 8);
      const float inv = 1.0f / l;
      const int qg = qrow0 + m * 16 + hi4 * 4 + i;
      __hip_bfloat16* orow = Og + ((size_t)b * S_LEN + qg) * D_MODEL + h * DK;
      for (int j = 0; j < 8; ++j)
        orow[j * 16 + lo16] = __float2bfloat16(oacc[m][j][i] * inv);
    }
  }
}

// ---------------------------------------------------------------------------
// Kernel 3: residual + LayerNorm, one block per row, vectorized loads
// ---------------------------------------------------------------------------
__global__ __launch_bounds__(256) void ln_kernel(
    const __hip_bfloat16* __restrict__ Og, const float* __restrict__ resid_in,
    const float* __restrict__ gamma, const float* __restrict__ beta,
    float* __restrict__ out) {
  const int row = blockIdx.x;
  const __hip_bfloat16* orow = Og + (size_t)row * D_MODEL;
  const float* qrow = resid_in + (size_t)row * D_MODEL;
  const int tid = threadIdx.x;
  const int base = tid * 4;
  const float4 q4 = *(const float4*)(qrow + base);
  const ushort4 o4 = *(const ushort4*)(orow + base);
  float v[4];
  v[0] = __bfloat162float(*(const __hip_bfloat16*)&o4.x) + q4.x;
  v[1] = __bfloat162float(*(const __hip_bfloat16*)&o4.y) + q4.y;
  v[2] = __bfloat162float(*(const __hip_bfloat16*)&o4.z) + q4.z;
  v[3] = __bfloat162float(*(const __hip_bfloat16*)&o4.w) + q4.w;
  float s = v[0] + v[1] + v[2] + v[3];
  float ss = v[0] * v[0] + v[1] * v[1] + v[2] * v[2] + v[3] * v[3];
  for (int m = 1; m < 64; m <<= 1) { s += __shfl_xor(s, m); ss += __shfl_xor(ss, m); }
  __shared__ float red[8];
  const int wv = tid >> 6, lane = tid & 63;
  if (lane == 0) { red[wv] = s; red[4 + wv] = ss; }
  __syncthreads();
  s  = red[0] + red[1] + red[2] + red[3];
  ss = red[4] + red[5] + red[6] + red[7];
  const float mu  = s * (1.0f / D_MODEL);
  const float var = ss * (1.0f / D_MODEL) - mu * mu;
  const float rstd = rsqrtf(var + 1e-6f);
  const float4 g4 = *(const float4*)(gamma + base);
  const float4 b4 = *(const float4*)(beta + base);
  float4 o;
  o.x = (v[0] - mu) * rstd * g4.x + b4.x;
  o.y = (v[1] - mu) * rstd * g4.y + b4.y;
  o.z = (v[2] - mu) * rstd * g4.z + b4.z;
  o.w = (v[3] - mu) * rstd * g4.w + b4.w;
  *(float4*)(out + (size_t)row * D_MODEL + base) = o;
}

// ---------------------------------------------------------------------------
extern "C" void kernel_launch(void* const* d_in, const int* in_sizes, int n_in,
                              void* d_out, int out_size, void* d_ws, size_t ws_size,
                              hipStream_t stream) {
  const float* queries = (const float*)d_in[0];
  const float* keys    = (const float*)d_in[1];
  const float* values  = (const float*)d_in[2];
  const float* Wq = (const float*)d_in[3];
  const float* bq = (const float*)d_in[4];
  const float* Wk = (const float*)d_in[5];
  const float* bk = (const float*)d_in[6];
  const float* Wv = (const float*)d_in[7];
  const float* bv = (const float*)d_in[8];
  const float* gamma = (const float*)d_in[9];
  const float* beta  = (const float*)d_in[10];

  char* ws = (char*)d_ws;
  const size_t N = (size_t)BATCH * S_LEN * D_MODEL;                 // 8M
  const size_t WT_BYTES  = (size_t)3 * D_MODEL * D_MODEL * 2;      // 6 MB
  const size_t XBF_BYTES = (size_t)3 * N * 2;                      // 48 MB
  const size_t QKV_BYTES = (size_t)BATCH * NH * S_LEN * DK * 2;    // 16 MB
  __hip_bfloat16* Wt  = (__hip_bfloat16*)ws;
  __hip_bfloat16* Xbf = (__hip_bfloat16*)(ws + WT_BYTES);
  // Og aliases the Xbf region (dead after qkv_gemm): 16 MB bf16
  __hip_bfloat16* Ogs = (__hip_bfloat16*)(ws + WT_BYTES);
  __hip_bfloat16* Qws = (__hip_bfloat16*)(ws + WT_BYTES + XBF_BYTES);
  __hip_bfloat16* Kws = (__hip_bfloat16*)(ws + WT_BYTES + XBF_BYTES + QKV_BYTES);
  __hip_bfloat16* Vws = (__hip_bfloat16*)(ws + WT_BYTES + XBF_BYTES + 2 * QKV_BYTES);
  // peak ws use: 6 + 48 + 48 = 102 MB

  cvt_kernel<<<dim3((unsigned)(N / 1024), 3), 256, 0, stream>>>(queries, keys, values, Xbf);
  wtrans_kernel<<<dim3(32, 32, 3), dim3(32, 8), 0, stream>>>(Wq, Wk, Wv, Wt);
  qkv_gemm_kernel<<<dim3(1536), 256, 0, stream>>>(
      Xbf, bq, bk, bv, Wt, Qws, Kws, Vws);
  attn_kernel<<<dim3(32, NH, BATCH), 128, 0, stream>>>(Qws, Kws, Vws, Ogs);
  ln_kernel<<<dim3(BATCH * S_LEN), 256, 0, stream>>>(Ogs, queries, gamma, beta,
                                                     (float*)d_out);
}

// Round 6
// 390.510 us; speedup vs baseline: 1.0979x; 1.0693x over previous
//
#include <hip/hip_runtime.h>
#include <hip/hip_bf16.h>
#include <stdint.h>

#define D_MODEL 1024
#define S_LEN   2048
#define BATCH   4
#define NH      8
#define DK      128

typedef __attribute__((ext_vector_type(8))) __bf16 bf16x8;
typedef __attribute__((ext_vector_type(4))) float  f32x4;

__device__ __forceinline__ f32x4 mfma16(bf16x8 a, bf16x8 b, f32x4 c) {
  return __builtin_amdgcn_mfma_f32_16x16x32_bf16(a, b, c, 0, 0, 0);
}

// async global->LDS, 16B per lane; lds base is wave-uniform, HW writes
// ldsbase + lane*16 (guide §5, m97/m104).
__device__ __forceinline__ void gld_lds16(const void* g, void* l) {
  __builtin_amdgcn_global_load_lds(
      (const __attribute__((address_space(1))) void*)g,
      (__attribute__((address_space(3))) void*)l, 16, 0, 0);
}

#define ATTN_SCALE 0.08838834764831845f  // 1/sqrt(128), folded into Wq/bq

// ---------------------------------------------------------------------------
// Kernel 0a: fp32 -> bf16 convert of the three activation tensors.
// ---------------------------------------------------------------------------
__global__ __launch_bounds__(256) void cvt_kernel(
    const float* __restrict__ x0, const float* __restrict__ x1,
    const float* __restrict__ x2, __hip_bfloat16* __restrict__ out) {
  const size_t N = (size_t)BATCH * S_LEN * D_MODEL;  // 8M elems
  const int w = blockIdx.y;
  const float* src = (w == 0) ? x0 : (w == 1) ? x1 : x2;
  __hip_bfloat16* dst = out + (size_t)w * N;
  const size_t i = ((size_t)blockIdx.x * 256 + threadIdx.x) * 4;
  const float4 v = *(const float4*)(src + i);
  *(__hip_bfloat162*)(dst + i)     = __float22bfloat162_rn(make_float2(v.x, v.y));
  *(__hip_bfloat162*)(dst + i + 2) = __float22bfloat162_rn(make_float2(v.z, v.w));
}

// ---------------------------------------------------------------------------
// Kernel 0b: transpose+convert weights W[k][n] fp32 -> Wt[n][k] bf16.
// Wq pre-scaled by 1/sqrt(dk).
// ---------------------------------------------------------------------------
__global__ void wtrans_kernel(const float* __restrict__ Wq,
                              const float* __restrict__ Wk,
                              const float* __restrict__ Wv,
                              __hip_bfloat16* __restrict__ Wt) {
  __shared__ __hip_bfloat16 tile[32][33];
  const int w = blockIdx.z;
  const float* src = (w == 0) ? Wq : (w == 1) ? Wk : Wv;
  const float sc = (w == 0) ? ATTN_SCALE : 1.0f;
  __hip_bfloat16* dst = Wt + (size_t)w * D_MODEL * D_MODEL;
  const int tx = threadIdx.x, ty = threadIdx.y;
  int x = blockIdx.x * 32 + tx;
  int y = blockIdx.y * 32 + ty;
  for (int i = 0; i < 32; i += 8)
    tile[ty + i][tx] = __float2bfloat16(src[(size_t)(y + i) * D_MODEL + x] * sc);
  __syncthreads();
  x = blockIdx.y * 32 + tx;
  y = blockIdx.x * 32 + ty;
  for (int i = 0; i < 32; i += 8)
    dst[(size_t)(y + i) * D_MODEL + x] = tile[tx][ty + i];
}

// ---------------------------------------------------------------------------
// Kernel 1: QKV projection GEMM (m97 structure, bf16 staged A and B).
// XCD-grouped block order (R5). Q,K -> [B,H,S,dk]; V -> [B,H,dk,S].
// ---------------------------------------------------------------------------
__global__ __launch_bounds__(256) void qkv_gemm_kernel(
    const __hip_bfloat16* __restrict__ Xbf,
    const float* __restrict__ bq, const float* __restrict__ bk,
    const float* __restrict__ bv,
    const __hip_bfloat16* __restrict__ Wt,
    __hip_bfloat16* __restrict__ Qo, __hip_bfloat16* __restrict__ Ko,
    __hip_bfloat16* __restrict__ Vo) {
  const int flat = blockIdx.x;          // 0..1535
  const int xcd  = flat & 7;
  const int idx  = flat >> 3;           // 0..191
  const int n_t  = idx & 7;
  const int mg   = idx >> 3;            // 0..23
  const int pair = xcd * 24 + mg;       // 0..191 = 64 m-tiles x 3 slices
  const int which = pair >> 6;
  const int m_t   = pair & 63;

  const size_t N = (size_t)BATCH * S_LEN * D_MODEL;
  const __hip_bfloat16* X = Xbf + (size_t)which * N;
  const __hip_bfloat16* W = Wt + (size_t)which * D_MODEL * D_MODEL;
  const float* bias = (which == 0) ? bq : (which == 1) ? bk : bv;
  const float bscale = (which == 0) ? ATTN_SCALE : 1.0f;

  __shared__ __align__(16) __hip_bfloat16 Asm[128 * 32];
  __shared__ __align__(16) __hip_bfloat16 Bsm[128 * 32];

  const int tid  = threadIdx.x;
  const int lane = tid & 63;
  const int wv   = tid >> 6;
  const int lo16 = lane & 15;
  const int hi4  = lane >> 4;
  const int m0 = m_t * 128;
  const int n0 = n_t * 128;
  const int wm = (wv >> 1) * 64;
  const int wn = (wv & 1) * 64;

  f32x4 acc[4][4];
  const f32x4 z4 = {0.f, 0.f, 0.f, 0.f};
  for (int i = 0; i < 4; ++i)
    for (int j = 0; j < 4; ++j) acc[i][j] = z4;

  for (int k0 = 0; k0 < D_MODEL; k0 += 32) {
    __syncthreads();
    for (int it = 0; it < 2; ++it) {
      const int cbase = it * 256 + wv * 64;
      const int c = cbase + lane;
      gld_lds16(X + (size_t)(m0 + (c >> 2)) * D_MODEL + k0 + (c & 3) * 8,
                &Asm[cbase * 8]);
      gld_lds16(W + (size_t)(n0 + (c >> 2)) * D_MODEL + k0 + (c & 3) * 8,
                &Bsm[cbase * 8]);
    }
    __syncthreads();

    bf16x8 af[4], bfr[4];
    for (int i = 0; i < 4; ++i)
      af[i] = *(const bf16x8*)&Asm[(wm + 16 * i + lo16) * 32 + hi4 * 8];
    for (int j = 0; j < 4; ++j)
      bfr[j] = *(const bf16x8*)&Bsm[(wn + 16 * j + lo16) * 32 + hi4 * 8];
    for (int i = 0; i < 4; ++i)
      for (int j = 0; j < 4; ++j)
        acc[i][j] = mfma16(af[i], bfr[j], acc[i][j]);
  }

  const int b = m0 >> 11;
  for (int j = 0; j < 4; ++j) {
    const int n = n0 + wn + j * 16 + lo16;
    const float bval = bias[n] * bscale;
    const int h = n >> 7;
    const int d = n & 127;
    for (int i = 0; i < 4; ++i) {
      for (int r = 0; r < 4; ++r) {
        const int m = m0 + wm + 16 * i + hi4 * 4 + r;
        const int s = m & (S_LEN - 1);
        const __hip_bfloat16 ob = __float2bfloat16(acc[i][j][r] + bval);
        if (which == 0)
          Qo[((size_t)(b * NH + h) * S_LEN + s) * DK + d] = ob;
        else if (which == 1)
          Ko[((size_t)(b * NH + h) * S_LEN + s) * DK + d] = ob;
        else
          Vo[((size_t)(b * NH + h) * DK + d) * S_LEN + s] = ob;
      }
    }
  }
}

// ---------------------------------------------------------------------------
// Kernel 2: causal flash attention, DEEP-PREFETCH pipeline.
//  - block = one 128-row q-tile, 4 waves x 32 rows (R3 config, fastest).
//  - 3 KV LDS buffers, prefetch depth 2. Raw s_barrier + manual
//    s_waitcnt vmcnt(4): each stage() = exactly 4 global_load_lds per
//    thread, so vmcnt(4) waits for tile st while tile st+1 stays IN FLIGHT
//    across the barrier (the __syncthreads vmcnt(0) drain was ~90% of the
//    4.4 us step critical path per R3/R5 scaling fit).
//  - constant-max softmax: p = exp(s - 8); row-sum reduced once at the end.
//  - P C-layout -> A-layout via wave-local LDS + s_waitcnt lgkmcnt(0).
// ---------------------------------------------------------------------------
__global__ __launch_bounds__(256) void attn_kernel(
    const __hip_bfloat16* __restrict__ Qw, const __hip_bfloat16* __restrict__ Kw,
    const __hip_bfloat16* __restrict__ Vtw, __hip_bfloat16* __restrict__ Og) {
  const int t = 15 - blockIdx.x;        // 128-row q-tile, longest first
  const int h = blockIdx.y;
  const int b = blockIdx.z;
  const int tid  = threadIdx.x;
  const int lane = tid & 63;
  const int wv   = tid >> 6;
  const int lo16 = lane & 15;
  const int hi4  = lane >> 4;

  const int qrow0  = t * 128 + wv * 32;  // this wave's 32 q rows
  const int ns_w   = 4 * t + wv + 1;     // active kv32 steps for this wave
  const int nsteps = 4 * t + 4;          // block loop bound (>= 4)

  const size_t bh = (size_t)(b * NH + h);
  const __hip_bfloat16* Qp = Qw + bh * S_LEN * DK;
  const __hip_bfloat16* Kp = Kw + bh * S_LEN * DK;
  const __hip_bfloat16* Vp = Vtw + bh * DK * S_LEN;  // [dk][S]

  __shared__ __align__(16) __hip_bfloat16 Ksm[3][32 * 128];  // [dchunk16][kv32]
  __shared__ __align__(16) __hip_bfloat16 Vsm[3][128 * 32];  // [kvchunk4][d128]
  __shared__ __align__(16) __hip_bfloat16 Psm[4][32 * 40];   // per-wave P

  // Q fragments: A[m=lo16][k=hi4*8+j]; 2 m-groups x 4 k-steps cover 32q x 128d
  bf16x8 qf[2][4];
  for (int m = 0; m < 2; ++m)
    for (int kk = 0; kk < 4; ++kk)
      qf[m][kk] = *(const bf16x8*)&Qp[(size_t)(qrow0 + m * 16 + lo16) * DK +
                                      kk * 32 + hi4 * 8];

  f32x4 oacc[2][8];
  const f32x4 z4 = {0.f, 0.f, 0.f, 0.f};
  for (int m = 0; m < 2; ++m)
    for (int j = 0; j < 8; ++j) oacc[m][j] = z4;
  float lsum[2][4];
  for (int m = 0; m < 2; ++m)
    for (int i = 0; i < 4; ++i) lsum[m][i] = 0.f;

  // stage kv tile `st` into buffer `buf`: exactly 4 gld_lds16 per thread
  auto stage = [&](int st, int buf) {
    const int kv0 = st << 5;
    for (int it = 0; it < 2; ++it) {
      const int cbase = it * 256 + wv * 64;
      const int c = cbase + lane;
      gld_lds16(Kp + (size_t)(kv0 + (c & 31)) * DK + (c >> 5) * 8,
                &Ksm[buf][cbase * 8]);
      gld_lds16(Vp + (size_t)(c & 127) * S_LEN + kv0 + (c >> 7) * 8,
                &Vsm[buf][cbase * 8]);
    }
  };

  stage(0, 0);
  stage(1, 1);

  int bsel = 0;  // = st % 3
  for (int st = 0; st < nsteps; ++st) {
    // wait for tile st's 4 loads; leave tile st+1's 4 loads in flight
    if (st + 1 < nsteps)
      asm volatile("s_waitcnt vmcnt(4)" ::: "memory");
    else
      asm volatile("s_waitcnt vmcnt(0)" ::: "memory");
    __builtin_amdgcn_s_barrier();
    asm volatile("" ::: "memory");  // compiler fence: no LDS reads hoist above

    if (st < ns_w) {
      const __hip_bfloat16* Kb = Ksm[bsel];
      const __hip_bfloat16* Vb = Vsm[bsel];

      // QK^T: S[32q][32kv] as 2m x 2kn 16x16 tiles
      bf16x8 kf[2][4];
      for (int kn = 0; kn < 2; ++kn)
        for (int kk = 0; kk < 4; ++kk)
          kf[kn][kk] = *(const bf16x8*)&Kb[((kk * 4 + hi4) * 32 + kn * 16 + lo16) * 8];
      f32x4 sc[2][2];
      for (int m = 0; m < 2; ++m)
        for (int kn = 0; kn < 2; ++kn) {
          f32x4 s4 = z4;
          for (int kk = 0; kk < 4; ++kk)
            s4 = mfma16(qf[m][kk], kf[kn][kk], s4);
          sc[m][kn] = s4;
        }

      // constant-max softmax; C/D row = hi4*4+reg, col = lo16
      const int kv0 = st << 5;
      const bool do_mask = (st == ns_w - 1);  // only the diagonal step masks
      for (int m = 0; m < 2; ++m) {
        for (int i = 0; i < 4; ++i) {
          const int qg = qrow0 + m * 16 + hi4 * 4 + i;
          float s0 = sc[m][0][i];
          float s1 = sc[m][1][i];
          if (do_mask) {
            if (kv0 + lo16 > qg)      s0 = -1.0e30f;
            if (kv0 + 16 + lo16 > qg) s1 = -1.0e30f;
          }
          const float p0 = __expf(s0 - 8.f);
          const float p1 = __expf(s1 - 8.f);
          lsum[m][i] += p0 + p1;
          const int prw = m * 16 + hi4 * 4 + i;
          Psm[wv][prw * 40 + lo16]      = __float2bfloat16(p0);
          Psm[wv][prw * 40 + 16 + lo16] = __float2bfloat16(p1);
        }
      }
      // wave-local LDS round-trip: order + drain without any barrier
      asm volatile("s_waitcnt lgkmcnt(0)" ::: "memory");

      // PV: A = P[q16][kv32] per m-group, B = Vt[d][kv]; V frags shared by m
      bf16x8 pf[2];
      for (int m = 0; m < 2; ++m)
        pf[m] = *(const bf16x8*)&Psm[wv][(m * 16 + lo16) * 40 + hi4 * 8];
      for (int j = 0; j < 8; ++j) {
        const bf16x8 vf = *(const bf16x8*)&Vb[(hi4 * 128 + j * 16 + lo16) * 8];
        oacc[0][j] = mfma16(pf[0], vf, oacc[0][j]);
        oacc[1][j] = mfma16(pf[1], vf, oacc[1][j]);
      }
    }

    // prefetch tile st+2 into the buffer freed at step st-1 (all waves
    // passed the barrier above, so nobody still reads it)
    if (st + 2 < nsteps) {
      int nb = bsel + 2; if (nb >= 3) nb -= 3;
      stage(st + 2, nb);
    }
    if (++bsel == 3) bsel = 0;
  }

  // final row-sum reduce (over 16-lane groups) + O write
  for (int m = 0; m < 2; ++m) {
    for (int i = 0; i < 4; ++i) {
      float l = lsum[m][i];
      l += __shfl_xor(l, 1);
      l += __shfl_xor(l, 2);
      l += __shfl_xor(l, 4);
      l += __shfl_xor(l, 8);
      const float inv = 1.0f / l;
      const int qg = qrow0 + m * 16 + hi4 * 4 + i;
      __hip_bfloat16* orow = Og + ((size_t)b * S_LEN + qg) * D_MODEL + h * DK;
      for (int j = 0; j < 8; ++j)
        orow[j * 16 + lo16] = __float2bfloat16(oacc[m][j][i] * inv);
    }
  }
}

// ---------------------------------------------------------------------------
// Kernel 3: residual + LayerNorm, one block per row, vectorized loads
// ---------------------------------------------------------------------------
__global__ __launch_bounds__(256) void ln_kernel(
    const __hip_bfloat16* __restrict__ Og, const float* __restrict__ resid_in,
    const float* __restrict__ gamma, const float* __restrict__ beta,
    float* __restrict__ out) {
  const int row = blockIdx.x;
  const __hip_bfloat16* orow = Og + (size_t)row * D_MODEL;
  const float* qrow = resid_in + (size_t)row * D_MODEL;
  const int tid = threadIdx.x;
  const int base = tid * 4;
  const float4 q4 = *(const float4*)(qrow + base);
  const ushort4 o4 = *(const ushort4*)(orow + base);
  float v[4];
  v[0] = __bfloat162float(*(const __hip_bfloat16*)&o4.x) + q4.x;
  v[1] = __bfloat162float(*(const __hip_bfloat16*)&o4.y) + q4.y;
  v[2] = __bfloat162float(*(const __hip_bfloat16*)&o4.z) + q4.z;
  v[3] = __bfloat162float(*(const __hip_bfloat16*)&o4.w) + q4.w;
  float s = v[0] + v[1] + v[2] + v[3];
  float ss = v[0] * v[0] + v[1] * v[1] + v[2] * v[2] + v[3] * v[3];
  for (int m = 1; m < 64; m <<= 1) { s += __shfl_xor(s, m); ss += __shfl_xor(ss, m); }
  __shared__ float red[8];
  const int wv = tid >> 6, lane = tid & 63;
  if (lane == 0) { red[wv] = s; red[4 + wv] = ss; }
  __syncthreads();
  s  = red[0] + red[1] + red[2] + red[3];
  ss = red[4] + red[5] + red[6] + red[7];
  const float mu  = s * (1.0f / D_MODEL);
  const float var = ss * (1.0f / D_MODEL) - mu * mu;
  const float rstd = rsqrtf(var + 1e-6f);
  const float4 g4 = *(const float4*)(gamma + base);
  const float4 b4 = *(const float4*)(beta + base);
  float4 o;
  o.x = (v[0] - mu) * rstd * g4.x + b4.x;
  o.y = (v[1] - mu) * rstd * g4.y + b4.y;
  o.z = (v[2] - mu) * rstd * g4.z + b4.z;
  o.w = (v[3] - mu) * rstd * g4.w + b4.w;
  *(float4*)(out + (size_t)row * D_MODEL + base) = o;
}

// ---------------------------------------------------------------------------
extern "C" void kernel_launch(void* const* d_in, const int* in_sizes, int n_in,
                              void* d_out, int out_size, void* d_ws, size_t ws_size,
                              hipStream_t stream) {
  const float* queries = (const float*)d_in[0];
  const float* keys    = (const float*)d_in[1];
  const float* values  = (const float*)d_in[2];
  const float* Wq = (const float*)d_in[3];
  const float* bq = (const float*)d_in[4];
  const float* Wk = (const float*)d_in[5];
  const float* bk = (const float*)d_in[6];
  const float* Wv = (const float*)d_in[7];
  const float* bv = (const float*)d_in[8];
  const float* gamma = (const float*)d_in[9];
  const float* beta  = (const float*)d_in[10];

  char* ws = (char*)d_ws;
  const size_t N = (size_t)BATCH * S_LEN * D_MODEL;                 // 8M
  const size_t WT_BYTES  = (size_t)3 * D_MODEL * D_MODEL * 2;      // 6 MB
  const size_t XBF_BYTES = (size_t)3 * N * 2;                      // 48 MB
  const size_t QKV_BYTES = (size_t)BATCH * NH * S_LEN * DK * 2;    // 16 MB
  __hip_bfloat16* Wt  = (__hip_bfloat16*)ws;
  __hip_bfloat16* Xbf = (__hip_bfloat16*)(ws + WT_BYTES);
  __hip_bfloat16* Ogs = (__hip_bfloat16*)(ws + WT_BYTES);  // aliases dead Xbf
  __hip_bfloat16* Qws = (__hip_bfloat16*)(ws + WT_BYTES + XBF_BYTES);
  __hip_bfloat16* Kws = (__hip_bfloat16*)(ws + WT_BYTES + XBF_BYTES + QKV_BYTES);
  __hip_bfloat16* Vws = (__hip_bfloat16*)(ws + WT_BYTES + XBF_BYTES + 2 * QKV_BYTES);

  cvt_kernel<<<dim3((unsigned)(N / 1024), 3), 256, 0, stream>>>(queries, keys, values, Xbf);
  wtrans_kernel<<<dim3(32, 32, 3), dim3(32, 8), 0, stream>>>(Wq, Wk, Wv, Wt);
  qkv_gemm_kernel<<<dim3(1536), 256, 0, stream>>>(
      Xbf, bq, bk, bv, Wt, Qws, Kws, Vws);
  attn_kernel<<<dim3(16, NH, BATCH), 256, 0, stream>>>(Qws, Kws, Vws, Ogs);
  ln_kernel<<<dim3(BATCH * S_LEN), 256, 0, stream>>>(Ogs, queries, gamma, beta,
                                                     (float*)d_out);
}